// Round 4
// baseline (349.263 us; speedup 1.0000x reference)
//
#include <hip/hip_runtime.h>

// TopKRouter: logits = hs[32768,4096] @ gate_w[64,4096]^T ; top-2 + softmax.
// f32 GEMM via 3-limb truncation split (6 MFMA products, si+sj<=2), numerics
// identical to the verified R3 kernel (same split, same product/accum order).
//
// R4 structure: NO LDS / NO barriers in the main loop. Each lane of a wave
// loads its own MFMA A-fragment (8 contiguous f32 of one row) directly from
// global, converts in-register, and feeds MFMA. gate_w is pre-split once
// into 3 bf16 limb planes in d_ws (1.5 MiB, L2-resident) by a pre-kernel.
// This sidesteps the compiler's vmcnt(0) drain at __syncthreads (the R3
// bottleneck): loads stay in flight across the whole pipeline.

#define NT   256
#define TT   32768
#define HD   4096
#define NE   64
#define BMT  64
#define BKT  32
#define NKT  (HD / BKT)      // 128 K-steps
#define WLIMB (NE * HD)      // ushort elems per B limb plane = 262144

typedef __attribute__((ext_vector_type(8))) short bf16x8;
typedef __attribute__((ext_vector_type(4))) float f32x4;

#define MFMA __builtin_amdgcn_mfma_f32_16x16x32_bf16

__device__ __forceinline__ bf16x8 u2b(uint4 u) {
  return __builtin_bit_cast(bf16x8, u);
}

// Exact 3-limb truncation split of 8 f32 -> 3 packed bf16x8 (as uint4).
__device__ __forceinline__ void tsplit8(float4 a, float4 b,
                                        uint4& o0, uint4& o1, uint4& o2) {
  float f[8] = {a.x, a.y, a.z, a.w, b.x, b.y, b.z, b.w};
  unsigned p0[4], p1[4], p2[4];
#pragma unroll
  for (int j = 0; j < 4; ++j) {
    float x0 = f[2 * j], x1 = f[2 * j + 1];
    unsigned u0 = __float_as_uint(x0) & 0xffff0000u;
    unsigned u1 = __float_as_uint(x1) & 0xffff0000u;
    float r0 = x0 - __uint_as_float(u0);
    float r1 = x1 - __uint_as_float(u1);
    unsigned v0 = __float_as_uint(r0) & 0xffff0000u;
    unsigned v1 = __float_as_uint(r1) & 0xffff0000u;
    float s0 = r0 - __uint_as_float(v0);
    float s1 = r1 - __uint_as_float(v1);
    p0[j] = (u0 >> 16) | u1;
    p1[j] = (v0 >> 16) | v1;
    p2[j] = (__float_as_uint(s0) >> 16) | (__float_as_uint(s1) & 0xffff0000u);
  }
  o0 = make_uint4(p0[0], p0[1], p0[2], p0[3]);
  o1 = make_uint4(p1[0], p1[1], p1[2], p1[3]);
  o2 = make_uint4(p2[0], p2[1], p2[2], p2[3]);
}

// ---- Pre-kernel: split gate_w into 3 bf16 limb planes in d_ws ----
__global__ __launch_bounds__(256)
void presplit_w_kernel(const float* __restrict__ W, uint4* __restrict__ Wl) {
  const int t = blockIdx.x * 256 + threadIdx.x;   // 0..32767, 8 elems each
  const float4* wp = (const float4*)W + 2 * (size_t)t;
  float4 v0 = wp[0], v1 = wp[1];
  uint4 o0, o1, o2;
  tsplit8(v0, v1, o0, o1, o2);
  Wl[t]                   = o0;
  Wl[t + WLIMB / 8]       = o1;
  Wl[t + 2 * (WLIMB / 8)] = o2;
}

// ---- Main kernel: barrier-free direct-fragment GEMM + top-2 ----
__global__ __launch_bounds__(NT, 2)
void router_direct_kernel(const float* __restrict__ A, const ushort* __restrict__ Wl,
                          float* __restrict__ outw, float* __restrict__ outi,
                          float* __restrict__ outl) {
  __shared__ float lf[BMT * 65];   // epilogue only

  const int tid  = threadIdx.x;
  const int bm   = blockIdx.x;
  const int lane = tid & 63;
  const int wid  = tid >> 6;     // 0..3
  const int wr   = wid >> 1;     // row half
  const int wc   = wid & 1;      // expert half
  const int l15  = lane & 15;
  const int lg   = lane >> 4;    // 0..3

  const int r0 = bm * BMT + wr * 32;   // wave's 32 rows
  const int e0 = wc * 32;              // wave's 32 experts

  // A fragment pointers (lane owns 8 contiguous f32 of one row):
  const float* pa0 = A + (size_t)(r0 + l15) * HD + lg * 8;
  const float* pa1 = pa0 + (size_t)16 * HD;
  // B limb fragment pointers:
  const ushort* pb0 = Wl + (size_t)(e0 + l15) * HD + lg * 8;
  const ushort* pb1 = pb0 + (size_t)16 * HD;

  f32x4 acc00 = {0.f,0.f,0.f,0.f}, acc01 = {0.f,0.f,0.f,0.f};
  f32x4 acc10 = {0.f,0.f,0.f,0.f}, acc11 = {0.f,0.f,0.f,0.f};

  float4 aE00, aE01, aE10, aE11, aO00, aO01, aO10, aO11;
  bf16x8 bE00, bE01, bE02, bE10, bE11, bE12;
  bf16x8 bO00, bO01, bO02, bO10, bO11, bO12;

#define LOADA(K, S) { \
    const float4* p0 = (const float4*)(pa0 + (size_t)(K) * BKT); \
    const float4* p1 = (const float4*)(pa1 + (size_t)(K) * BKT); \
    a##S##00 = p0[0]; a##S##01 = p0[1]; \
    a##S##10 = p1[0]; a##S##11 = p1[1]; }

#define LOADB(K, S) { \
    const ushort* q0 = pb0 + (size_t)(K) * BKT; \
    const ushort* q1 = pb1 + (size_t)(K) * BKT; \
    b##S##00 = *(const bf16x8*)(q0); \
    b##S##01 = *(const bf16x8*)(q0 + WLIMB); \
    b##S##02 = *(const bf16x8*)(q0 + 2 * WLIMB); \
    b##S##10 = *(const bf16x8*)(q1); \
    b##S##11 = *(const bf16x8*)(q1 + WLIMB); \
    b##S##12 = *(const bf16x8*)(q1 + 2 * WLIMB); }

#define PROD1(AM0, AM1, BS0, BS1) \
    acc00 = MFMA(AM0, BS0, acc00, 0, 0, 0); \
    acc01 = MFMA(AM0, BS1, acc01, 0, 0, 0); \
    acc10 = MFMA(AM1, BS0, acc10, 0, 0, 0); \
    acc11 = MFMA(AM1, BS1, acc11, 0, 0, 0);

  // Convert A raw -> limbs in-register, then 6 limb products
  // (smallest-magnitude first; order identical to R3's verified kernel).
#define STEP(S) { \
    uint4 x0, x1, x2, y0, y1, y2; \
    tsplit8(a##S##00, a##S##01, x0, x1, x2); \
    tsplit8(a##S##10, a##S##11, y0, y1, y2); \
    const bf16x8 a00 = u2b(x0), a01 = u2b(x1), a02 = u2b(x2); \
    const bf16x8 a10 = u2b(y0), a11 = u2b(y1), a12 = u2b(y2); \
    PROD1(a00, a10, b##S##02, b##S##12) \
    PROD1(a01, a11, b##S##01, b##S##11) \
    PROD1(a02, a12, b##S##00, b##S##10) \
    PROD1(a00, a10, b##S##01, b##S##11) \
    PROD1(a01, a11, b##S##00, b##S##10) \
    PROD1(a00, a10, b##S##00, b##S##10) }

  LOADA(0, E) LOADB(0, E)
#pragma unroll 1
  for (int kt = 0; kt < NKT; kt += 2) {
    LOADA(kt + 1, O) LOADB(kt + 1, O)
    STEP(E)
    if (kt + 2 < NKT) { LOADA(kt + 2, E) LOADB(kt + 2, E) }
    STEP(O)
    __builtin_amdgcn_s_barrier();   // raw: phase-lock waves (L1 dup hits), NO waitcnt drain
  }

  // ---- Epilogue: logits to global + LDS, then top-2 + softmax ----
  const int t0 = bm * BMT;

#define EPI(MI, NI, ACC) \
  { _Pragma("unroll") \
    for (int r = 0; r < 4; ++r) { \
      int tl = wr * 32 + (MI) * 16 + lg * 4 + r; \
      int e  = wc * 32 + (NI) * 16 + l15; \
      float v = ACC[r]; \
      outl[(size_t)(t0 + tl) * NE + e] = v; \
      lf[tl * 65 + e] = v; \
    } }
  EPI(0, 0, acc00) EPI(0, 1, acc01) EPI(1, 0, acc10) EPI(1, 1, acc11)
#undef EPI

  __syncthreads();

  if (tid < BMT) {
    const int t = tid;
    float m1 = -1e30f, m2 = -1e30f;
    int i1 = 0, i2 = 0;
#pragma unroll
    for (int e = 0; e < NE; ++e) {
      float v = lf[t * 65 + e];
      if (v > m1)      { m2 = m1; i2 = i1; m1 = v; i1 = e; }
      else if (v > m2) { m2 = v; i2 = e; }
    }
    float e2  = expf(m2 - m1);
    float inv = 1.0f / (1.0f + e2);
    outw[(size_t)(t0 + t) * 2 + 0] = inv;
    outw[(size_t)(t0 + t) * 2 + 1] = e2 * inv;
    outi[(size_t)(t0 + t) * 2 + 0] = (float)i1;   // indices as floats
    outi[(size_t)(t0 + t) * 2 + 1] = (float)i2;
  }
}

// ---- Fallback (R3 LDS kernel, verified): used only if ws_size too small ----
__global__ __launch_bounds__(NT, 2)
void topk_router_lds(const float* __restrict__ A, const float* __restrict__ W,
                     float* __restrict__ outw, float* __restrict__ outi,
                     float* __restrict__ outl) {
  __shared__ __align__(16) unsigned char smem[49152];
  const int tid  = threadIdx.x;
  const int bm   = blockIdx.x;
  const int lane = tid & 63;
  const int wid  = tid >> 6;
  const int wr   = wid >> 1;
  const int wc   = wid & 1;
  const int l15  = lane & 15;
  const int lg   = lane >> 4;
  const int s_r  = tid >> 2;
  const int s_cb = (tid & 3) << 3;
  const float* aball = A + (size_t)(bm * BMT + s_r) * HD + s_cb;
  const float* bball = W + (size_t)s_r * HD + s_cb;
  const unsigned wswz  = ((unsigned)((s_r >> 1) & 3)) << 4;
  const unsigned wbyte = (unsigned)(s_r * 64) + (((unsigned)(s_cb * 2)) ^ wswz);
  f32x4 acc00 = {0.f,0.f,0.f,0.f}, acc01 = {0.f,0.f,0.f,0.f};
  f32x4 acc10 = {0.f,0.f,0.f,0.f}, acc11 = {0.f,0.f,0.f,0.f};
  float4 aE0, aE1, bE0, bE1, aO0, aO1, bO0, bO1;
#define LOADS(T, A0, A1, B0, B1) { \
    const float4* ap = (const float4*)(aball + (size_t)(T) * BKT); \
    A0 = ap[0]; A1 = ap[1]; \
    const float4* bp = (const float4*)(bball + (size_t)(T) * BKT); \
    B0 = bp[0]; B1 = bp[1]; }
#define CONVW(BB, A0, A1, B0, B1) { \
    uint4 o0, o1, o2; \
    tsplit8(A0, A1, o0, o1, o2); \
    *(uint4*)(smem + (BB) +     0 + wbyte) = o0; \
    *(uint4*)(smem + (BB) +  4096 + wbyte) = o1; \
    *(uint4*)(smem + (BB) +  8192 + wbyte) = o2; \
    tsplit8(B0, B1, o0, o1, o2); \
    *(uint4*)(smem + (BB) + 12288 + wbyte) = o0; \
    *(uint4*)(smem + (BB) + 16384 + wbyte) = o1; \
    *(uint4*)(smem + (BB) + 20480 + wbyte) = o2; }
  auto compute = [&](int bb) {
    bf16x8 a0m0, a0m1, a1m0, a1m1, a2m0, a2m1;
    bf16x8 b0n0, b0n1, b1n0, b1n1, b2n0, b2n1;
    const unsigned kb = (unsigned)(lg * 16);
#define LDA(SI, MI, DST) { \
    int row = wr * 32 + (MI) * 16 + l15; \
    DST = *(const bf16x8*)(smem + bb + (SI) * 4096 + row * 64 + \
          (kb ^ ((((unsigned)row >> 1) & 3) << 4))); }
#define LDB(SI, NI, DST) { \
    int row = wc * 32 + (NI) * 16 + l15; \
    DST = *(const bf16x8*)(smem + bb + 12288 + (SI) * 4096 + row * 64 + \
          (kb ^ ((((unsigned)row >> 1) & 3) << 4))); }
    LDA(0, 0, a0m0) LDA(0, 1, a0m1)
    LDA(1, 0, a1m0) LDA(1, 1, a1m1)
    LDA(2, 0, a2m0) LDA(2, 1, a2m1)
    LDB(0, 0, b0n0) LDB(0, 1, b0n1)
    LDB(1, 0, b1n0) LDB(1, 1, b1n1)
    LDB(2, 0, b2n0) LDB(2, 1, b2n1)
#undef LDA
#undef LDB
    PROD1(a0m0, a0m1, b2n0, b2n1)
    PROD1(a1m0, a1m1, b1n0, b1n1)
    PROD1(a2m0, a2m1, b0n0, b0n1)
    PROD1(a0m0, a0m1, b1n0, b1n1)
    PROD1(a1m0, a1m1, b0n0, b0n1)
    PROD1(a0m0, a0m1, b0n0, b0n1)
  };
  LOADS(0, aE0, aE1, bE0, bE1)
  LOADS(1, aO0, aO1, bO0, bO1)
  CONVW(0, aE0, aE1, bE0, bE1)
  __syncthreads();
#pragma unroll 1
  for (int kk = 0; kk < NKT; kk += 2) {
    if (kk + 2 < NKT) { LOADS(kk + 2, aE0, aE1, bE0, bE1) }
    __builtin_amdgcn_sched_barrier(0);
    compute(0);
    CONVW(24576, aO0, aO1, bO0, bO1)
    __syncthreads();
    if (kk + 3 < NKT) { LOADS(kk + 3, aO0, aO1, bO0, bO1) }
    __builtin_amdgcn_sched_barrier(0);
    compute(24576);
    if (kk + 2 < NKT) { CONVW(0, aE0, aE1, bE0, bE1) }
    __syncthreads();
  }
  const int t0 = bm * BMT;
  float* lf2 = (float*)smem;
#define EPI(MI, NI, ACC) \
  { _Pragma("unroll") \
    for (int r = 0; r < 4; ++r) { \
      int tl = wr * 32 + (MI) * 16 + lg * 4 + r; \
      int e  = wc * 32 + (NI) * 16 + l15; \
      float v = ACC[r]; \
      outl[(size_t)(t0 + tl) * NE + e] = v; \
      lf2[tl * 65 + e] = v; \
    } }
  EPI(0, 0, acc00) EPI(0, 1, acc01) EPI(1, 0, acc10) EPI(1, 1, acc11)
#undef EPI
  __syncthreads();
  if (tid < BMT) {
    const int t = tid;
    float m1 = -1e30f, m2 = -1e30f;
    int i1 = 0, i2 = 0;
#pragma unroll
    for (int e = 0; e < NE; ++e) {
      float v = lf2[t * 65 + e];
      if (v > m1)      { m2 = m1; i2 = i1; m1 = v; i1 = e; }
      else if (v > m2) { m2 = v; i2 = e; }
    }
    float e2  = expf(m2 - m1);
    float inv = 1.0f / (1.0f + e2);
    outw[(size_t)(t0 + t) * 2 + 0] = inv;
    outw[(size_t)(t0 + t) * 2 + 1] = e2 * inv;
    outi[(size_t)(t0 + t) * 2 + 0] = (float)i1;
    outi[(size_t)(t0 + t) * 2 + 1] = (float)i2;
  }
}

extern "C" void kernel_launch(void* const* d_in, const int* in_sizes, int n_in,
                              void* d_out, int out_size, void* d_ws, size_t ws_size,
                              hipStream_t stream) {
  (void)in_sizes; (void)n_in; (void)out_size;
  const float* A = (const float*)d_in[0];   // hidden_states [32768][4096] f32
  const float* W = (const float*)d_in[1];   // gate_w [64][4096] f32
  float* outw = (float*)d_out;              // [T][2] weights
  float* outi = (float*)d_out + 2 * TT;     // [T][2] indices AS FLOATS
  float* outl = (float*)d_out + 4 * TT;     // [T][64] logits

  const size_t need = (size_t)3 * WLIMB * sizeof(ushort);  // 1.5 MiB
  if (ws_size >= need) {
    hipLaunchKernelGGL(presplit_w_kernel, dim3(128), dim3(256), 0, stream,
                       W, (uint4*)d_ws);
    hipLaunchKernelGGL(router_direct_kernel, dim3(TT / BMT), dim3(NT), 0, stream,
                       A, (const ushort*)d_ws, outw, outi, outl);
  } else {
    hipLaunchKernelGGL(topk_router_lds, dim3(TT / BMT), dim3(NT), 0, stream,
                       A, W, outw, outi, outl);
  }
}

// Round 5
// 228.228 us; speedup vs baseline: 1.5303x; 1.5303x over previous
//
#include <hip/hip_runtime.h>

// TopKRouter: logits = hs[32768,4096] @ gate_w[64,4096]^T ; top-2 + softmax.
// f32 GEMM via 3-limb truncation split (6 MFMA products, si+sj<=2); limb
// values and accumulation order bit-identical to the verified R3 kernel.
//
// R5: A staged through LDS (coalesced, swizzled, double-buffered 24 KiB),
// B pre-split once into 3 bf16 limb planes in d_ws (1.5 MiB, L2-resident)
// and loaded direct-to-register one full iteration ahead.  Main loop uses
// RAW s_barrier + lgkmcnt(0)-only fences (no __syncthreads) so the k+2
// A-loads stay in flight across the barrier -- removes the vmcnt(0) drain
// that bounded R3 at 168 us.

#define NT   256
#define TT   32768
#define HD   4096
#define NE   64
#define BMT  64
#define BKT  32
#define NKT  (HD / BKT)      // 128 K-steps
#define WLIMB (NE * HD)      // ushort elems per B limb plane = 262144

typedef __attribute__((ext_vector_type(8))) short bf16x8;
typedef __attribute__((ext_vector_type(4))) float f32x4;

#define MFMA __builtin_amdgcn_mfma_f32_16x16x32_bf16

__device__ __forceinline__ bf16x8 u2b(uint4 u) {
  return __builtin_bit_cast(bf16x8, u);
}

// Exact 3-limb truncation split of 8 f32 -> 3 packed bf16x8 (as uint4).
__device__ __forceinline__ void tsplit8(float4 a, float4 b,
                                        uint4& o0, uint4& o1, uint4& o2) {
  float f[8] = {a.x, a.y, a.z, a.w, b.x, b.y, b.z, b.w};
  unsigned p0[4], p1[4], p2[4];
#pragma unroll
  for (int j = 0; j < 4; ++j) {
    float x0 = f[2 * j], x1 = f[2 * j + 1];
    unsigned u0 = __float_as_uint(x0) & 0xffff0000u;
    unsigned u1 = __float_as_uint(x1) & 0xffff0000u;
    float r0 = x0 - __uint_as_float(u0);
    float r1 = x1 - __uint_as_float(u1);
    unsigned v0 = __float_as_uint(r0) & 0xffff0000u;
    unsigned v1 = __float_as_uint(r1) & 0xffff0000u;
    float s0 = r0 - __uint_as_float(v0);
    float s1 = r1 - __uint_as_float(v1);
    p0[j] = (u0 >> 16) | u1;
    p1[j] = (v0 >> 16) | v1;
    p2[j] = (__float_as_uint(s0) >> 16) | (__float_as_uint(s1) & 0xffff0000u);
  }
  o0 = make_uint4(p0[0], p0[1], p0[2], p0[3]);
  o1 = make_uint4(p1[0], p1[1], p1[2], p1[3]);
  o2 = make_uint4(p2[0], p2[1], p2[2], p2[3]);
}

// ---- Pre-kernel: split gate_w into 3 bf16 limb planes in d_ws ----
__global__ __launch_bounds__(256)
void presplit_w_kernel(const float* __restrict__ W, uint4* __restrict__ Wl) {
  const int t = blockIdx.x * 256 + threadIdx.x;   // 0..32767, 8 elems each
  const float4* wp = (const float4*)W + 2 * (size_t)t;
  float4 v0 = wp[0], v1 = wp[1];
  uint4 o0, o1, o2;
  tsplit8(v0, v1, o0, o1, o2);
  Wl[t]                   = o0;
  Wl[t + WLIMB / 8]       = o1;
  Wl[t + 2 * (WLIMB / 8)] = o2;
}

// Raw barrier: drain LDS ops only; VMEM (global loads) stay in flight.
#define SOFT_BARRIER() do { \
    asm volatile("s_waitcnt lgkmcnt(0)" ::: "memory"); \
    __builtin_amdgcn_s_barrier(); \
    asm volatile("" ::: "memory"); \
  } while (0)

// LDS: 2 buffers x 12 KiB (A limbs only). Per buffer: limb s at s*4096,
// tile [64 rows][32 bf16] = 64 B/row. Swizzle: byte ^= ((row>>1)&3)<<4.

__global__ __launch_bounds__(NT, 2)
void router_hybrid_kernel(const float* __restrict__ A, const ushort* __restrict__ Wl,
                          float* __restrict__ outw, float* __restrict__ outi,
                          float* __restrict__ outl) {
  __shared__ __align__(16) unsigned char smem[24576];

  const int tid  = threadIdx.x;
  const int bm   = blockIdx.x;
  const int lane = tid & 63;
  const int wid  = tid >> 6;     // 0..3
  const int wr   = wid >> 1;     // row half
  const int wc   = wid & 1;      // expert half
  const int l15  = lane & 15;
  const int lg   = lane >> 4;    // 0..3

  // A staging: thread owns 8 f32 of one row.
  const int s_r  = tid >> 2;           // 0..63
  const int s_cb = (tid & 3) << 3;     // element offset {0,8,16,24}
  const float* aball = A + (size_t)(bm * BMT + s_r) * HD + s_cb;
  const unsigned wswz  = ((unsigned)((s_r >> 1) & 3)) << 4;
  const unsigned wbyte = (unsigned)(s_r * 64) + (((unsigned)(s_cb * 2)) ^ wswz);

  // B limb fragment pointers (direct from pre-split planes, L2-resident).
  const int e0 = wc * 32;
  const ushort* pb0 = Wl + (size_t)(e0 + l15) * HD + lg * 8;
  const ushort* pb1 = pb0 + (size_t)16 * HD;

  f32x4 acc00 = {0.f,0.f,0.f,0.f}, acc01 = {0.f,0.f,0.f,0.f};
  f32x4 acc10 = {0.f,0.f,0.f,0.f}, acc11 = {0.f,0.f,0.f,0.f};

  float4 aE0, aE1, aO0, aO1;                     // A raw (even/odd tiles)
  bf16x8 bE00, bE01, bE02, bE10, bE11, bE12;     // B limbs, even tiles
  bf16x8 bO00, bO01, bO02, bO10, bO11, bO12;     // B limbs, odd tiles

#define LOADA(T, S) { \
    const float4* ap = (const float4*)(aball + (size_t)(T) * BKT); \
    a##S##0 = ap[0]; a##S##1 = ap[1]; }

#define LOADB(T, S) { \
    const ushort* q0 = pb0 + (size_t)(T) * BKT; \
    const ushort* q1 = pb1 + (size_t)(T) * BKT; \
    b##S##00 = *(const bf16x8*)(q0); \
    b##S##01 = *(const bf16x8*)(q0 + WLIMB); \
    b##S##02 = *(const bf16x8*)(q0 + 2 * WLIMB); \
    b##S##10 = *(const bf16x8*)(q1); \
    b##S##11 = *(const bf16x8*)(q1 + WLIMB); \
    b##S##12 = *(const bf16x8*)(q1 + 2 * WLIMB); }

#define CONVW(BB, S) { \
    uint4 o0, o1, o2; \
    tsplit8(a##S##0, a##S##1, o0, o1, o2); \
    *(uint4*)(smem + (BB) +    0 + wbyte) = o0; \
    *(uint4*)(smem + (BB) + 4096 + wbyte) = o1; \
    *(uint4*)(smem + (BB) + 8192 + wbyte) = o2; }

#define PROD1(AM0, AM1, BS0, BS1) \
    acc00 = MFMA(AM0, BS0, acc00, 0, 0, 0); \
    acc01 = MFMA(AM0, BS1, acc01, 0, 0, 0); \
    acc10 = MFMA(AM1, BS0, acc10, 0, 0, 0); \
    acc11 = MFMA(AM1, BS1, acc11, 0, 0, 0);

  // Compute one tile from LDS buffer bb with B limb set S (in regs).
  // Product order: smallest-magnitude first (identical to R3).
#define COMPUTE(bb, S) { \
    bf16x8 a0m0, a0m1, a1m0, a1m1, a2m0, a2m1; \
    const unsigned kb = (unsigned)(lg * 16); \
    { int row = wr * 32 + 0  + l15; unsigned sz = (kb ^ ((((unsigned)row >> 1) & 3) << 4)); \
      a0m0 = *(const bf16x8*)(smem + (bb) +    0 + row * 64 + sz); \
      a1m0 = *(const bf16x8*)(smem + (bb) + 4096 + row * 64 + sz); \
      a2m0 = *(const bf16x8*)(smem + (bb) + 8192 + row * 64 + sz); } \
    { int row = wr * 32 + 16 + l15; unsigned sz = (kb ^ ((((unsigned)row >> 1) & 3) << 4)); \
      a0m1 = *(const bf16x8*)(smem + (bb) +    0 + row * 64 + sz); \
      a1m1 = *(const bf16x8*)(smem + (bb) + 4096 + row * 64 + sz); \
      a2m1 = *(const bf16x8*)(smem + (bb) + 8192 + row * 64 + sz); } \
    PROD1(a0m0, a0m1, b##S##02, b##S##12) \
    PROD1(a1m0, a1m1, b##S##01, b##S##11) \
    PROD1(a2m0, a2m1, b##S##00, b##S##10) \
    PROD1(a0m0, a0m1, b##S##01, b##S##11) \
    PROD1(a1m0, a1m1, b##S##00, b##S##10) \
    PROD1(a0m0, a0m1, b##S##00, b##S##10) }

  // Prologue: A tiles 0,1 + B tiles 0,1 in flight; convert tile 0 -> buf0.
  LOADA(0, E) LOADA(1, O)
  LOADB(0, E) LOADB(1, O)
  CONVW(0, E)
  SOFT_BARRIER();

#pragma unroll 1
  for (int kt = 0; kt < NKT; kt += 2) {
    // ---- even half: compute tile kt (buf0, BE); stage tile kt+1 -> buf1 ----
    if (kt + 2 < NKT) { LOADA(kt + 2, E) }
    __builtin_amdgcn_sched_barrier(0);
    COMPUTE(0, E)
    if (kt + 2 < NKT) { LOADB(kt + 2, E) }
    CONVW(12288, O)                       // counted vmcnt: waits only O A-loads
    SOFT_BARRIER();
    // ---- odd half: compute tile kt+1 (buf1, BO); stage tile kt+2 -> buf0 ----
    if (kt + 3 < NKT) { LOADA(kt + 3, O) }
    __builtin_amdgcn_sched_barrier(0);
    COMPUTE(12288, O)
    if (kt + 3 < NKT) { LOADB(kt + 3, O) }
    if (kt + 2 < NKT) { CONVW(0, E) }
    SOFT_BARRIER();
  }

  // ---- Epilogue: logits to global + LDS, then top-2 + softmax ----
  const int t0 = bm * BMT;
  float* lf = (float*)smem;              // reuse: [64][65] f32... needs 16.6KB < 24KB

#define EPI(MI, NI, ACC) \
  { _Pragma("unroll") \
    for (int r = 0; r < 4; ++r) { \
      int tl = wr * 32 + (MI) * 16 + lg * 4 + r; \
      int e  = wc * 32 + (NI) * 16 + l15; \
      float v = ACC[r]; \
      outl[(size_t)(t0 + tl) * NE + e] = v; \
      lf[tl * 65 + e] = v; \
    } }
  EPI(0, 0, acc00) EPI(0, 1, acc01) EPI(1, 0, acc10) EPI(1, 1, acc11)
#undef EPI

  __syncthreads();

  if (tid < BMT) {
    const int t = tid;
    float m1 = -1e30f, m2 = -1e30f;
    int i1 = 0, i2 = 0;
#pragma unroll
    for (int e = 0; e < NE; ++e) {
      float v = lf[t * 65 + e];
      if (v > m1)      { m2 = m1; i2 = i1; m1 = v; i1 = e; }
      else if (v > m2) { m2 = v; i2 = e; }
    }
    float e2  = expf(m2 - m1);
    float inv = 1.0f / (1.0f + e2);
    outw[(size_t)(t0 + t) * 2 + 0] = inv;
    outw[(size_t)(t0 + t) * 2 + 1] = e2 * inv;
    outi[(size_t)(t0 + t) * 2 + 0] = (float)i1;   // indices as floats
    outi[(size_t)(t0 + t) * 2 + 1] = (float)i2;
  }
}

// ---- Fallback (R3 LDS kernel, verified): used only if ws_size too small ----
__global__ __launch_bounds__(NT, 2)
void topk_router_lds(const float* __restrict__ A, const float* __restrict__ W,
                     float* __restrict__ outw, float* __restrict__ outi,
                     float* __restrict__ outl) {
  __shared__ __align__(16) unsigned char smem[49152];
  const int tid  = threadIdx.x;
  const int bm   = blockIdx.x;
  const int lane = tid & 63;
  const int wid  = tid >> 6;
  const int wr   = wid >> 1;
  const int wc   = wid & 1;
  const int l15  = lane & 15;
  const int lg   = lane >> 4;
  const int s_r  = tid >> 2;
  const int s_cb = (tid & 3) << 3;
  const float* aball = A + (size_t)(bm * BMT + s_r) * HD + s_cb;
  const float* bball = W + (size_t)s_r * HD + s_cb;
  const unsigned wswz  = ((unsigned)((s_r >> 1) & 3)) << 4;
  const unsigned wbyte = (unsigned)(s_r * 64) + (((unsigned)(s_cb * 2)) ^ wswz);
  f32x4 acc00 = {0.f,0.f,0.f,0.f}, acc01 = {0.f,0.f,0.f,0.f};
  f32x4 acc10 = {0.f,0.f,0.f,0.f}, acc11 = {0.f,0.f,0.f,0.f};
  float4 aE0, aE1, bE0, bE1, aO0, aO1, bO0, bO1;
#define LOADS(T, A0, A1, B0, B1) { \
    const float4* ap = (const float4*)(aball + (size_t)(T) * BKT); \
    A0 = ap[0]; A1 = ap[1]; \
    const float4* bp = (const float4*)(bball + (size_t)(T) * BKT); \
    B0 = bp[0]; B1 = bp[1]; }
#define CONVW2(BB, A0, A1, B0, B1) { \
    uint4 o0, o1, o2; \
    tsplit8(A0, A1, o0, o1, o2); \
    *(uint4*)(smem + (BB) +     0 + wbyte) = o0; \
    *(uint4*)(smem + (BB) +  4096 + wbyte) = o1; \
    *(uint4*)(smem + (BB) +  8192 + wbyte) = o2; \
    tsplit8(B0, B1, o0, o1, o2); \
    *(uint4*)(smem + (BB) + 12288 + wbyte) = o0; \
    *(uint4*)(smem + (BB) + 16384 + wbyte) = o1; \
    *(uint4*)(smem + (BB) + 20480 + wbyte) = o2; }
  auto compute = [&](int bb) {
    bf16x8 a0m0, a0m1, a1m0, a1m1, a2m0, a2m1;
    bf16x8 b0n0, b0n1, b1n0, b1n1, b2n0, b2n1;
    const unsigned kb = (unsigned)(lg * 16);
#define LDA(SI, MI, DST) { \
    int row = wr * 32 + (MI) * 16 + l15; \
    DST = *(const bf16x8*)(smem + bb + (SI) * 4096 + row * 64 + \
          (kb ^ ((((unsigned)row >> 1) & 3) << 4))); }
#define LDB(SI, NI, DST) { \
    int row = wc * 32 + (NI) * 16 + l15; \
    DST = *(const bf16x8*)(smem + bb + 12288 + (SI) * 4096 + row * 64 + \
          (kb ^ ((((unsigned)row >> 1) & 3) << 4))); }
    LDA(0, 0, a0m0) LDA(0, 1, a0m1)
    LDA(1, 0, a1m0) LDA(1, 1, a1m1)
    LDA(2, 0, a2m0) LDA(2, 1, a2m1)
    LDB(0, 0, b0n0) LDB(0, 1, b0n1)
    LDB(1, 0, b1n0) LDB(1, 1, b1n1)
    LDB(2, 0, b2n0) LDB(2, 1, b2n1)
#undef LDA
#undef LDB
    PROD1(a0m0, a0m1, b2n0, b2n1)
    PROD1(a1m0, a1m1, b1n0, b1n1)
    PROD1(a2m0, a2m1, b0n0, b0n1)
    PROD1(a0m0, a0m1, b1n0, b1n1)
    PROD1(a1m0, a1m1, b0n0, b0n1)
    PROD1(a0m0, a0m1, b0n0, b0n1)
  };
  LOADS(0, aE0, aE1, bE0, bE1)
  LOADS(1, aO0, aO1, bO0, bO1)
  CONVW2(0, aE0, aE1, bE0, bE1)
  __syncthreads();
#pragma unroll 1
  for (int kk = 0; kk < NKT; kk += 2) {
    if (kk + 2 < NKT) { LOADS(kk + 2, aE0, aE1, bE0, bE1) }
    __builtin_amdgcn_sched_barrier(0);
    compute(0);
    CONVW2(24576, aO0, aO1, bO0, bO1)
    __syncthreads();
    if (kk + 3 < NKT) { LOADS(kk + 3, aO0, aO1, bO0, bO1) }
    __builtin_amdgcn_sched_barrier(0);
    compute(24576);
    if (kk + 2 < NKT) { CONVW2(0, aE0, aE1, bE0, bE1) }
    __syncthreads();
  }
  const int t0 = bm * BMT;
  float* lf2 = (float*)smem;
#define EPI(MI, NI, ACC) \
  { _Pragma("unroll") \
    for (int r = 0; r < 4; ++r) { \
      int tl = wr * 32 + (MI) * 16 + lg * 4 + r; \
      int e  = wc * 32 + (NI) * 16 + l15; \
      float v = ACC[r]; \
      outl[(size_t)(t0 + tl) * NE + e] = v; \
      lf2[tl * 65 + e] = v; \
    } }
  EPI(0, 0, acc00) EPI(0, 1, acc01) EPI(1, 0, acc10) EPI(1, 1, acc11)
#undef EPI
  __syncthreads();
  if (tid < BMT) {
    const int t = tid;
    float m1 = -1e30f, m2 = -1e30f;
    int i1 = 0, i2 = 0;
#pragma unroll
    for (int e = 0; e < NE; ++e) {
      float v = lf2[t * 65 + e];
      if (v > m1)      { m2 = m1; i2 = i1; m1 = v; i1 = e; }
      else if (v > m2) { m2 = v; i2 = e; }
    }
    float e2  = expf(m2 - m1);
    float inv = 1.0f / (1.0f + e2);
    outw[(size_t)(t0 + t) * 2 + 0] = inv;
    outw[(size_t)(t0 + t) * 2 + 1] = e2 * inv;
    outi[(size_t)(t0 + t) * 2 + 0] = (float)i1;
    outi[(size_t)(t0 + t) * 2 + 1] = (float)i2;
  }
}

extern "C" void kernel_launch(void* const* d_in, const int* in_sizes, int n_in,
                              void* d_out, int out_size, void* d_ws, size_t ws_size,
                              hipStream_t stream) {
  (void)in_sizes; (void)n_in; (void)out_size;
  const float* A = (const float*)d_in[0];   // hidden_states [32768][4096] f32
  const float* W = (const float*)d_in[1];   // gate_w [64][4096] f32
  float* outw = (float*)d_out;              // [T][2] weights
  float* outi = (float*)d_out + 2 * TT;     // [T][2] indices AS FLOATS
  float* outl = (float*)d_out + 4 * TT;     // [T][64] logits

  const size_t need = (size_t)3 * WLIMB * sizeof(ushort);  // 1.5 MiB
  if (ws_size >= need) {
    hipLaunchKernelGGL(presplit_w_kernel, dim3(128), dim3(256), 0, stream,
                       W, (uint4*)d_ws);
    hipLaunchKernelGGL(router_hybrid_kernel, dim3(TT / BMT), dim3(NT), 0, stream,
                       A, (const ushort*)d_ws, outw, outi, outl);
  } else {
    hipLaunchKernelGGL(topk_router_lds, dim3(TT / BMT), dim3(NT), 0, stream,
                       A, W, outw, outi, outl);
  }
}

// Round 6
// 202.980 us; speedup vs baseline: 1.7207x; 1.1244x over previous
//
#include <hip/hip_runtime.h>

// TopKRouter: logits = hs[32768,4096] @ gate_w[64,4096]^T ; top-2 + softmax.
// f32 GEMM via 3-limb truncation split (6 MFMA products, si+sj<=2); limb
// values and accumulation order bit-identical to the verified R3 kernel.
//
// R6 schedule: "consume-before-barrier". Per K-step: issue coalesced loads
// (B limbs from pre-split planes in ws, A raw f32) at phase top; COMPUTE
// current LDS buffer (independent of those loads); then convert/copy the
// loads into the other LDS buffer (counted vmcnt overlaps the whole compute
// phase); then __syncthreads -- at which point NOTHING is outstanding, so
// the compiler's vmcnt(0) drain is free. No load ever crosses a barrier.
// B is never converted in the hot loop (pre-split once, staged coalesced).

#define NT   256
#define TT   32768
#define HD   4096
#define NE   64
#define BMT  64
#define BKT  32
#define NKT  (HD / BKT)      // 128 K-steps
#define WLIMB (NE * HD)      // ushort elems per B limb plane = 262144
#define BUFB 24576           // bytes per LDS buffer

typedef __attribute__((ext_vector_type(8))) short bf16x8;
typedef __attribute__((ext_vector_type(4))) float f32x4;

#define MFMA __builtin_amdgcn_mfma_f32_16x16x32_bf16

// Exact 3-limb truncation split of 8 f32 -> 3 packed bf16x8 (as uint4).
__device__ __forceinline__ void tsplit8(float4 a, float4 b,
                                        uint4& o0, uint4& o1, uint4& o2) {
  float f[8] = {a.x, a.y, a.z, a.w, b.x, b.y, b.z, b.w};
  unsigned p0[4], p1[4], p2[4];
#pragma unroll
  for (int j = 0; j < 4; ++j) {
    float x0 = f[2 * j], x1 = f[2 * j + 1];
    unsigned u0 = __float_as_uint(x0) & 0xffff0000u;
    unsigned u1 = __float_as_uint(x1) & 0xffff0000u;
    float r0 = x0 - __uint_as_float(u0);
    float r1 = x1 - __uint_as_float(u1);
    unsigned v0 = __float_as_uint(r0) & 0xffff0000u;
    unsigned v1 = __float_as_uint(r1) & 0xffff0000u;
    float s0 = r0 - __uint_as_float(v0);
    float s1 = r1 - __uint_as_float(v1);
    p0[j] = (u0 >> 16) | u1;
    p1[j] = (v0 >> 16) | v1;
    p2[j] = (__float_as_uint(s0) >> 16) | (__float_as_uint(s1) & 0xffff0000u);
  }
  o0 = make_uint4(p0[0], p0[1], p0[2], p0[3]);
  o1 = make_uint4(p1[0], p1[1], p1[2], p1[3]);
  o2 = make_uint4(p2[0], p2[1], p2[2], p2[3]);
}

// ---- Pre-kernel: split gate_w into 3 bf16 limb planes in d_ws ----
__global__ __launch_bounds__(256)
void presplit_w_kernel(const float* __restrict__ W, uint4* __restrict__ Wl) {
  const int t = blockIdx.x * 256 + threadIdx.x;   // 0..32767, 8 elems each
  const float4* wp = (const float4*)W + 2 * (size_t)t;
  float4 v0 = wp[0], v1 = wp[1];
  uint4 o0, o1, o2;
  tsplit8(v0, v1, o0, o1, o2);
  Wl[t]                   = o0;
  Wl[t + WLIMB / 8]       = o1;
  Wl[t + 2 * (WLIMB / 8)] = o2;
}

// LDS per buffer (24 KiB): A limbs s=0..2 at s*4096, B limbs at 12288+s*4096.
// Tile [64 rows][32 bf16] = 64 B/row. Swizzle: byte ^= ((row>>1)&3)<<4,
// applied on write (wbyte) and read (COMPUTE) alike.

__global__ __launch_bounds__(NT, 2)
void router_cbb_kernel(const float* __restrict__ A, const ushort* __restrict__ Wl,
                       float* __restrict__ outw, float* __restrict__ outi,
                       float* __restrict__ outl) {
  __shared__ __align__(16) unsigned char smem[49152];

  const int tid  = threadIdx.x;
  const int bm   = blockIdx.x;
  const int lane = tid & 63;
  const int wid  = tid >> 6;     // 0..3
  const int wr   = wid >> 1;     // row half
  const int wc   = wid & 1;      // expert half
  const int l15  = lane & 15;
  const int lg   = lane >> 4;    // 0..3

  // Coalesced staging: thread owns 8 elems of one row (A: f32, B: ushort/plane).
  const int s_r  = tid >> 2;           // 0..63
  const int s_cb = (tid & 3) << 3;     // element offset {0,8,16,24}
  const float*  aball = A  + (size_t)(bm * BMT + s_r) * HD + s_cb;
  const ushort* wlp   = Wl + (size_t)s_r * HD + s_cb;
  const unsigned wswz  = ((unsigned)((s_r >> 1) & 3)) << 4;
  const unsigned wbyte = (unsigned)(s_r * 64) + (((unsigned)(s_cb * 2)) ^ wswz);

  f32x4 acc00 = {0.f,0.f,0.f,0.f}, acc01 = {0.f,0.f,0.f,0.f};
  f32x4 acc10 = {0.f,0.f,0.f,0.f}, acc11 = {0.f,0.f,0.f,0.f};

  float4 aR0, aR1;          // A raw (consumed same phase)
  uint4  bR0, bR1, bR2;     // B limbs (consumed same phase)

  // Issue order: B first (fast, L2), A second (slow, HBM); consumption order
  // WRITEB (vmcnt waits only B) then CONVA (vmcnt(0), waits A last).
#define LOADB(T) { \
    const ushort* q = wlp + (size_t)(T) * BKT; \
    bR0 = *(const uint4*)(q); \
    bR1 = *(const uint4*)(q + WLIMB); \
    bR2 = *(const uint4*)(q + 2 * WLIMB); }

#define LOADA(T) { \
    const float4* ap = (const float4*)(aball + (size_t)(T) * BKT); \
    aR0 = ap[0]; aR1 = ap[1]; }

#define WRITEB(BB) { \
    *(uint4*)(smem + (BB) + 12288 + wbyte) = bR0; \
    *(uint4*)(smem + (BB) + 16384 + wbyte) = bR1; \
    *(uint4*)(smem + (BB) + 20480 + wbyte) = bR2; }

#define CONVA(BB) { \
    uint4 o0, o1, o2; \
    tsplit8(aR0, aR1, o0, o1, o2); \
    *(uint4*)(smem + (BB) +    0 + wbyte) = o0; \
    *(uint4*)(smem + (BB) + 4096 + wbyte) = o1; \
    *(uint4*)(smem + (BB) + 8192 + wbyte) = o2; }

#define PROD1(AM0, AM1, BS0, BS1) \
    acc00 = MFMA(AM0, BS0, acc00, 0, 0, 0); \
    acc01 = MFMA(AM0, BS1, acc01, 0, 0, 0); \
    acc10 = MFMA(AM1, BS0, acc10, 0, 0, 0); \
    acc11 = MFMA(AM1, BS1, acc11, 0, 0, 0);

  // Product order: smallest-magnitude first (identical to R3).
#define COMPUTE(bb) { \
    bf16x8 a0m0, a0m1, a1m0, a1m1, a2m0, a2m1; \
    bf16x8 b0n0, b0n1, b1n0, b1n1, b2n0, b2n1; \
    const unsigned kb = (unsigned)(lg * 16); \
    { int row = wr * 32 + 0  + l15; unsigned sz = (kb ^ ((((unsigned)row >> 1) & 3) << 4)); \
      a0m0 = *(const bf16x8*)(smem + (bb) +    0 + row * 64 + sz); \
      a1m0 = *(const bf16x8*)(smem + (bb) + 4096 + row * 64 + sz); \
      a2m0 = *(const bf16x8*)(smem + (bb) + 8192 + row * 64 + sz); } \
    { int row = wr * 32 + 16 + l15; unsigned sz = (kb ^ ((((unsigned)row >> 1) & 3) << 4)); \
      a0m1 = *(const bf16x8*)(smem + (bb) +    0 + row * 64 + sz); \
      a1m1 = *(const bf16x8*)(smem + (bb) + 4096 + row * 64 + sz); \
      a2m1 = *(const bf16x8*)(smem + (bb) + 8192 + row * 64 + sz); } \
    { int row = wc * 32 + 0  + l15; unsigned sz = (kb ^ ((((unsigned)row >> 1) & 3) << 4)); \
      b0n0 = *(const bf16x8*)(smem + (bb) + 12288 + row * 64 + sz); \
      b1n0 = *(const bf16x8*)(smem + (bb) + 16384 + row * 64 + sz); \
      b2n0 = *(const bf16x8*)(smem + (bb) + 20480 + row * 64 + sz); } \
    { int row = wc * 32 + 16 + l15; unsigned sz = (kb ^ ((((unsigned)row >> 1) & 3) << 4)); \
      b0n1 = *(const bf16x8*)(smem + (bb) + 12288 + row * 64 + sz); \
      b1n1 = *(const bf16x8*)(smem + (bb) + 16384 + row * 64 + sz); \
      b2n1 = *(const bf16x8*)(smem + (bb) + 20480 + row * 64 + sz); } \
    PROD1(a0m0, a0m1, b2n0, b2n1) \
    PROD1(a1m0, a1m1, b1n0, b1n1) \
    PROD1(a2m0, a2m1, b0n0, b0n1) \
    PROD1(a0m0, a0m1, b1n0, b1n1) \
    PROD1(a1m0, a1m1, b0n0, b0n1) \
    PROD1(a0m0, a0m1, b0n0, b0n1) }

  // Prologue: stage tile 0 -> buf0.
  LOADB(0) LOADA(0)
  WRITEB(0) CONVA(0)
  __syncthreads();

#pragma unroll 1
  for (int k = 0; k < NKT; k += 2) {
    // even: compute buf0; stage k+1 -> buf1 (loads consumed before barrier)
    LOADB(k + 1) LOADA(k + 1)
    __builtin_amdgcn_sched_barrier(0);
    COMPUTE(0)
    WRITEB(BUFB) CONVA(BUFB)
    __syncthreads();
    // odd: compute buf1; stage k+2 -> buf0
    if (k + 2 < NKT) { LOADB(k + 2) LOADA(k + 2) }
    __builtin_amdgcn_sched_barrier(0);
    COMPUTE(BUFB)
    if (k + 2 < NKT) { WRITEB(0) CONVA(0) }
    __syncthreads();
  }

  // ---- Epilogue: logits to global + LDS, then top-2 + softmax ----
  const int t0 = bm * BMT;
  float* lf = (float*)smem;            // [64][65] f32 (16.6 KB), pad kills conflicts

#define EPI(MI, NI, ACC) \
  { _Pragma("unroll") \
    for (int r = 0; r < 4; ++r) { \
      int tl = wr * 32 + (MI) * 16 + lg * 4 + r; \
      int e  = wc * 32 + (NI) * 16 + l15; \
      float v = ACC[r]; \
      outl[(size_t)(t0 + tl) * NE + e] = v; \
      lf[tl * 65 + e] = v; \
    } }
  EPI(0, 0, acc00) EPI(0, 1, acc01) EPI(1, 0, acc10) EPI(1, 1, acc11)
#undef EPI

  __syncthreads();

  if (tid < BMT) {
    const int t = tid;
    float m1 = -1e30f, m2 = -1e30f;
    int i1 = 0, i2 = 0;
#pragma unroll
    for (int e = 0; e < NE; ++e) {
      float v = lf[t * 65 + e];
      if (v > m1)      { m2 = m1; i2 = i1; m1 = v; i1 = e; }
      else if (v > m2) { m2 = v; i2 = e; }
    }
    float e2  = expf(m2 - m1);
    float inv = 1.0f / (1.0f + e2);
    outw[(size_t)(t0 + t) * 2 + 0] = inv;
    outw[(size_t)(t0 + t) * 2 + 1] = e2 * inv;
    outi[(size_t)(t0 + t) * 2 + 0] = (float)i1;   // indices as floats
    outi[(size_t)(t0 + t) * 2 + 1] = (float)i2;
  }
}

// ---- Fallback (R3 LDS kernel, verified): used only if ws_size too small ----
__global__ __launch_bounds__(NT, 2)
void topk_router_lds(const float* __restrict__ A, const float* __restrict__ W,
                     float* __restrict__ outw, float* __restrict__ outi,
                     float* __restrict__ outl) {
  __shared__ __align__(16) unsigned char smem[49152];
  const int tid  = threadIdx.x;
  const int bm   = blockIdx.x;
  const int lane = tid & 63;
  const int wid  = tid >> 6;
  const int wr   = wid >> 1;
  const int wc   = wid & 1;
  const int l15  = lane & 15;
  const int lg   = lane >> 4;
  const int s_r  = tid >> 2;
  const int s_cb = (tid & 3) << 3;
  const float* aball = A + (size_t)(bm * BMT + s_r) * HD + s_cb;
  const float* bball = W + (size_t)s_r * HD + s_cb;
  const unsigned wswz  = ((unsigned)((s_r >> 1) & 3)) << 4;
  const unsigned wbyte = (unsigned)(s_r * 64) + (((unsigned)(s_cb * 2)) ^ wswz);
  f32x4 acc00 = {0.f,0.f,0.f,0.f}, acc01 = {0.f,0.f,0.f,0.f};
  f32x4 acc10 = {0.f,0.f,0.f,0.f}, acc11 = {0.f,0.f,0.f,0.f};
  float4 aE0, aE1, bE0, bE1, aO0, aO1, bO0, bO1;
#define LOADS(T, A0, A1, B0, B1) { \
    const float4* ap = (const float4*)(aball + (size_t)(T) * BKT); \
    A0 = ap[0]; A1 = ap[1]; \
    const float4* bp = (const float4*)(bball + (size_t)(T) * BKT); \
    B0 = bp[0]; B1 = bp[1]; }
#define CONVW2(BB, A0, A1, B0, B1) { \
    uint4 o0, o1, o2; \
    tsplit8(A0, A1, o0, o1, o2); \
    *(uint4*)(smem + (BB) +     0 + wbyte) = o0; \
    *(uint4*)(smem + (BB) +  4096 + wbyte) = o1; \
    *(uint4*)(smem + (BB) +  8192 + wbyte) = o2; \
    tsplit8(B0, B1, o0, o1, o2); \
    *(uint4*)(smem + (BB) + 12288 + wbyte) = o0; \
    *(uint4*)(smem + (BB) + 16384 + wbyte) = o1; \
    *(uint4*)(smem + (BB) + 20480 + wbyte) = o2; }
  auto compute = [&](int bb) {
    bf16x8 a0m0, a0m1, a1m0, a1m1, a2m0, a2m1;
    bf16x8 b0n0, b0n1, b1n0, b1n1, b2n0, b2n1;
    const unsigned kb = (unsigned)(lg * 16);
#define LDA(SI, MI, DST) { \
    int row = wr * 32 + (MI) * 16 + l15; \
    DST = *(const bf16x8*)(smem + bb + (SI) * 4096 + row * 64 + \
          (kb ^ ((((unsigned)row >> 1) & 3) << 4))); }
#define LDB(SI, NI, DST) { \
    int row = wc * 32 + (NI) * 16 + l15; \
    DST = *(const bf16x8*)(smem + bb + 12288 + (SI) * 4096 + row * 64 + \
          (kb ^ ((((unsigned)row >> 1) & 3) << 4))); }
    LDA(0, 0, a0m0) LDA(0, 1, a0m1)
    LDA(1, 0, a1m0) LDA(1, 1, a1m1)
    LDA(2, 0, a2m0) LDA(2, 1, a2m1)
    LDB(0, 0, b0n0) LDB(0, 1, b0n1)
    LDB(1, 0, b1n0) LDB(1, 1, b1n1)
    LDB(2, 0, b2n0) LDB(2, 1, b2n1)
#undef LDA
#undef LDB
    PROD1(a0m0, a0m1, b2n0, b2n1)
    PROD1(a1m0, a1m1, b1n0, b1n1)
    PROD1(a2m0, a2m1, b0n0, b0n1)
    PROD1(a0m0, a0m1, b1n0, b1n1)
    PROD1(a1m0, a1m1, b0n0, b0n1)
    PROD1(a0m0, a0m1, b0n0, b0n1)
  };
  LOADS(0, aE0, aE1, bE0, bE1)
  LOADS(1, aO0, aO1, bO0, bO1)
  CONVW2(0, aE0, aE1, bE0, bE1)
  __syncthreads();
#pragma unroll 1
  for (int kk = 0; kk < NKT; kk += 2) {
    if (kk + 2 < NKT) { LOADS(kk + 2, aE0, aE1, bE0, bE1) }
    __builtin_amdgcn_sched_barrier(0);
    compute(0);
    CONVW2(24576, aO0, aO1, bO0, bO1)
    __syncthreads();
    if (kk + 3 < NKT) { LOADS(kk + 3, aO0, aO1, bO0, bO1) }
    __builtin_amdgcn_sched_barrier(0);
    compute(24576);
    if (kk + 2 < NKT) { CONVW2(0, aE0, aE1, bE0, bE1) }
    __syncthreads();
  }
  const int t0 = bm * BMT;
  float* lf2 = (float*)smem;
#define EPI(MI, NI, ACC) \
  { _Pragma("unroll") \
    for (int r = 0; r < 4; ++r) { \
      int tl = wr * 32 + (MI) * 16 + lg * 4 + r; \
      int e  = wc * 32 + (NI) * 16 + l15; \
      float v = ACC[r]; \
      outl[(size_t)(t0 + tl) * NE + e] = v; \
      lf2[tl * 65 + e] = v; \
    } }
  EPI(0, 0, acc00) EPI(0, 1, acc01) EPI(1, 0, acc10) EPI(1, 1, acc11)
#undef EPI
  __syncthreads();
  if (tid < BMT) {
    const int t = tid;
    float m1 = -1e30f, m2 = -1e30f;
    int i1 = 0, i2 = 0;
#pragma unroll
    for (int e = 0; e < NE; ++e) {
      float v = lf2[t * 65 + e];
      if (v > m1)      { m2 = m1; i2 = i1; m1 = v; i1 = e; }
      else if (v > m2) { m2 = v; i2 = e; }
    }
    float e2  = expf(m2 - m1);
    float inv = 1.0f / (1.0f + e2);
    outw[(size_t)(t0 + t) * 2 + 0] = inv;
    outw[(size_t)(t0 + t) * 2 + 1] = e2 * inv;
    outi[(size_t)(t0 + t) * 2 + 0] = (float)i1;
    outi[(size_t)(t0 + t) * 2 + 1] = (float)i2;
  }
}

extern "C" void kernel_launch(void* const* d_in, const int* in_sizes, int n_in,
                              void* d_out, int out_size, void* d_ws, size_t ws_size,
                              hipStream_t stream) {
  (void)in_sizes; (void)n_in; (void)out_size;
  const float* A = (const float*)d_in[0];   // hidden_states [32768][4096] f32
  const float* W = (const float*)d_in[1];   // gate_w [64][4096] f32
  float* outw = (float*)d_out;              // [T][2] weights
  float* outi = (float*)d_out + 2 * TT;     // [T][2] indices AS FLOATS
  float* outl = (float*)d_out + 4 * TT;     // [T][64] logits

  const size_t need = (size_t)3 * WLIMB * sizeof(ushort);  // 1.5 MiB
  if (ws_size >= need) {
    hipLaunchKernelGGL(presplit_w_kernel, dim3(128), dim3(256), 0, stream,
                       W, (uint4*)d_ws);
    hipLaunchKernelGGL(router_cbb_kernel, dim3(TT / BMT), dim3(NT), 0, stream,
                       A, (const ushort*)d_ws, outw, outi, outl);
  } else {
    hipLaunchKernelGGL(topk_router_lds, dim3(TT / BMT), dim3(NT), 0, stream,
                       A, W, outw, outi, outl);
  }
}

// Round 7
// 197.524 us; speedup vs baseline: 1.7682x; 1.0276x over previous
//
#include <hip/hip_runtime.h>

// TopKRouter: logits = hs[32768,4096] @ gate_w[64,4096]^T ; top-2 + softmax.
// f32 GEMM via 3-limb truncation split (6 MFMA products, si+sj<=2); limb
// values and per-accumulator product order identical to verified R3 kernel.
//
// R7: A fragments loaded per-lane DIRECT from global (8 contiguous f32/lane,
// full cache-line use) -> tsplit in regs -> MFMA. No A LDS round trip.
// B pre-packed ONCE into MFMA-fragment-major bf16 limb blocks (1 KB per
// (k-step,limb,nfrag); 1.5 MB in d_ws, L2-resident); staged to LDS in 2-step
// chunks (24 KB, double-buffered, 48 KB static) via coalesced uint4 loads
// issued at chunk top + ds_write at chunk bottom. ONE barrier per 2 K-steps;
// everything crossing it has >=1 step (~1600 cyc) of lead.

#define NT    512
#define TT    32768
#define HD    4096
#define NE    64
#define BKT   32
#define NKT   128            // K-steps
#define KCH   2              // steps per chunk
#define NCH   (NKT / KCH)    // 64 chunks
#define BROWS 128            // rows per block (8 waves x 16 rows)
#define LDSBUF_U4 1536       // uint4 per LDS buffer (24 KB)

typedef __attribute__((ext_vector_type(8))) short bf16x8;
typedef __attribute__((ext_vector_type(4))) float f32x4;

#define MFMA __builtin_amdgcn_mfma_f32_16x16x32_bf16

__device__ __forceinline__ bf16x8 u2b(uint4 u) {
  return __builtin_bit_cast(bf16x8, u);
}

// Exact 3-limb truncation split of 8 f32 -> 3 packed bf16x8 (as uint4).
__device__ __forceinline__ void tsplit8(float4 a, float4 b,
                                        uint4& o0, uint4& o1, uint4& o2) {
  float f[8] = {a.x, a.y, a.z, a.w, b.x, b.y, b.z, b.w};
  unsigned p0[4], p1[4], p2[4];
#pragma unroll
  for (int j = 0; j < 4; ++j) {
    float x0 = f[2 * j], x1 = f[2 * j + 1];
    unsigned u0 = __float_as_uint(x0) & 0xffff0000u;
    unsigned u1 = __float_as_uint(x1) & 0xffff0000u;
    float r0 = x0 - __uint_as_float(u0);
    float r1 = x1 - __uint_as_float(u1);
    unsigned v0 = __float_as_uint(r0) & 0xffff0000u;
    unsigned v1 = __float_as_uint(r1) & 0xffff0000u;
    float s0 = r0 - __uint_as_float(v0);
    float s1 = r1 - __uint_as_float(v1);
    p0[j] = (u0 >> 16) | u1;
    p1[j] = (v0 >> 16) | v1;
    p2[j] = (__float_as_uint(s0) >> 16) | (__float_as_uint(s1) & 0xffff0000u);
  }
  o0 = make_uint4(p0[0], p0[1], p0[2], p0[3]);
  o1 = make_uint4(p1[0], p1[1], p1[2], p1[3]);
  o2 = make_uint4(p2[0], p2[1], p2[2], p2[3]);
}

// ---- Pre-kernel: pack gate_w into fragment-major bf16 limb blocks ----
// Block (t,s,f) = 1 KB: lane (lg*16+l15) holds bf16[8] = limb_s of
// W[f*16+l15][t*32+lg*8 .. +8].  uint4 index = ((t*3+s)*4+f)*64 + lane.
__global__ __launch_bounds__(256)
void prepack_w_kernel(const float* __restrict__ W, uint4* __restrict__ Bp) {
  const int t  = blockIdx.x * 256 + threadIdx.x;   // 0..32767
  const int e  = t >> 9;          // expert 0..63
  const int c8 = t & 511;         // k-chunk of 8
  const int k0 = c8 * 8;
  const float4* wp = (const float4*)(W + (size_t)e * HD + k0);
  uint4 o0, o1, o2;
  tsplit8(wp[0], wp[1], o0, o1, o2);
  const int ts = k0 >> 5;
  const int lg = (k0 >> 3) & 3;
  const int f  = e >> 4;
  const int ln = lg * 16 + (e & 15);
  Bp[(((ts * 3 + 0) * 4 + f) << 6) + ln] = o0;
  Bp[(((ts * 3 + 1) * 4 + f) << 6) + ln] = o1;
  Bp[(((ts * 3 + 2) * 4 + f) << 6) + ln] = o2;
}

// ---- Main kernel ----
__global__ __launch_bounds__(NT, 2)
void router_frag_kernel(const float* __restrict__ A, const uint4* __restrict__ Bp,
                        float* __restrict__ outw, float* __restrict__ outi,
                        float* __restrict__ outl) {
  __shared__ __align__(16) uint4 smem[2 * LDSBUF_U4];   // 48 KB static

  const int tid  = threadIdx.x;
  const int bm   = blockIdx.x;
  const int lane = tid & 63;
  const int w    = tid >> 6;     // wave 0..7
  const int l15  = lane & 15;
  const int lg   = lane >> 4;    // 0..3

  // A fragment pointer: lane owns 8 contiguous f32 of its row.
  const int row = bm * BROWS + w * 16 + l15;
  const float* pa = A + (size_t)row * HD + lg * 8;

  // B staging: chunk c = 1536 uint4; wave w copies 192 (3 instrs x 64 lanes).
  const uint4* bsrc = Bp + w * 192 + lane;

  f32x4 acc0 = {0.f,0.f,0.f,0.f}, acc1 = {0.f,0.f,0.f,0.f};
  f32x4 acc2 = {0.f,0.f,0.f,0.f}, acc3 = {0.f,0.f,0.f,0.f};

  uint4 st0, st1, st2;   // staged B chunk (consumed same chunk, pre-barrier)

#define SLOAD(CH) { \
    const uint4* q_ = bsrc + (size_t)(CH) * LDSBUF_U4; \
    st0 = q_[0]; st1 = q_[64]; st2 = q_[128]; }

#define SWRITE(BUFI) { \
    uint4* d_ = smem + (BUFI) * LDSBUF_U4 + w * 192 + lane; \
    d_[0] = st0; d_[64] = st1; d_[128] = st2; }

  // 3 B-limb fragment reads + 6 MFMA for one n-frag; product order
  // smallest-magnitude first (identical to R3's verified order).
#define FRAG(T4, F, ACC, A0_, A1_, A2_) { \
    const bf16x8 q0_ = bbx[(((T4) * 3 + 0) * 4 + (F)) * 64 + lane]; \
    const bf16x8 q1_ = bbx[(((T4) * 3 + 1) * 4 + (F)) * 64 + lane]; \
    const bf16x8 q2_ = bbx[(((T4) * 3 + 2) * 4 + (F)) * 64 + lane]; \
    ACC = MFMA(A0_, q2_, ACC, 0, 0, 0); \
    ACC = MFMA(A1_, q1_, ACC, 0, 0, 0); \
    ACC = MFMA(A2_, q0_, ACC, 0, 0, 0); \
    ACC = MFMA(A0_, q1_, ACC, 0, 0, 0); \
    ACC = MFMA(A1_, q0_, ACC, 0, 0, 0); \
    ACC = MFMA(A0_, q0_, ACC, 0, 0, 0); }

  // One K-step: prefetch A(t+1), split A(t) in regs, 12 ds_reads, 24 MFMA.
#define STEP(T4, AX0, AX1, AY0, AY1) { \
    int tn_ = t0s + (T4) + 1; if (tn_ >= NKT) tn_ = NKT - 1; \
    const float4* ap_ = (const float4*)(pa + (size_t)tn_ * BKT); \
    AY0 = ap_[0]; AY1 = ap_[1]; \
    uint4 x0_, x1_, x2_; \
    tsplit8(AX0, AX1, x0_, x1_, x2_); \
    const bf16x8 a0_ = u2b(x0_), a1_ = u2b(x1_), a2_ = u2b(x2_); \
    FRAG(T4, 0, acc0, a0_, a1_, a2_) \
    FRAG(T4, 1, acc1, a0_, a1_, a2_) \
    FRAG(T4, 2, acc2, a0_, a1_, a2_) \
    FRAG(T4, 3, acc3, a0_, a1_, a2_) }

  // Prologue: stage chunk 0, prefetch A step 0.
  SLOAD(0)
  SWRITE(0)
  float4 aX0, aX1, aY0, aY1;
  { const float4* ap = (const float4*)pa; aX0 = ap[0]; aX1 = ap[1]; }
  __syncthreads();

#pragma unroll 1
  for (int c = 0; c < NCH; ++c) {
    const bf16x8* bbx = (const bf16x8*)(smem + (c & 1) * LDSBUF_U4);
    const int t0s = c * KCH;
    const bool more = (c + 1 < NCH);
    if (more) { SLOAD(c + 1) }          // issued chunk-top: ~2 steps of lead
    __builtin_amdgcn_sched_barrier(0);
    STEP(0, aX0, aX1, aY0, aY1)
    STEP(1, aY0, aY1, aX0, aX1)
    if (more) { SWRITE((c + 1) & 1) }   // consumed pre-barrier: drain is free
    __syncthreads();
  }

  // ---- Epilogue: logits to global + LDS, then top-2 + softmax ----
  const int tb = bm * BROWS;
  float* lf = (float*)smem;             // [128][65] f32 = 33.3 KB < 48 KB
  const int rbase = w * 16 + lg * 4;

#define EPO(F, ACC) { \
    _Pragma("unroll") \
    for (int r = 0; r < 4; ++r) { \
      int tl = rbase + r; int e = (F) * 16 + l15; float v = ACC[r]; \
      outl[(size_t)(tb + tl) * NE + e] = v; \
      lf[tl * 65 + e] = v; \
    } }
  EPO(0, acc0) EPO(1, acc1) EPO(2, acc2) EPO(3, acc3)
#undef EPO

  __syncthreads();

  if (tid < BROWS) {
    const int t = tid;
    float m1 = -1e30f, m2 = -1e30f;
    int i1 = 0, i2 = 0;
#pragma unroll
    for (int e = 0; e < NE; ++e) {
      float v = lf[t * 65 + e];
      if (v > m1)      { m2 = m1; i2 = i1; m1 = v; i1 = e; }
      else if (v > m2) { m2 = v; i2 = e; }
    }
    float e2  = expf(m2 - m1);
    float inv = 1.0f / (1.0f + e2);
    outw[(size_t)(tb + t) * 2 + 0] = inv;
    outw[(size_t)(tb + t) * 2 + 1] = e2 * inv;
    outi[(size_t)(tb + t) * 2 + 0] = (float)i1;   // indices as floats
    outi[(size_t)(tb + t) * 2 + 1] = (float)i2;
  }
}

// ---- Fallback (R3 LDS kernel, verified): used only if ws_size too small ----
#define PROD1(AM0, AM1, BS0, BS1) \
    acc00 = MFMA(AM0, BS0, acc00, 0, 0, 0); \
    acc01 = MFMA(AM0, BS1, acc01, 0, 0, 0); \
    acc10 = MFMA(AM1, BS0, acc10, 0, 0, 0); \
    acc11 = MFMA(AM1, BS1, acc11, 0, 0, 0);

__global__ __launch_bounds__(256, 2)
void topk_router_lds(const float* __restrict__ A, const float* __restrict__ W,
                     float* __restrict__ outw, float* __restrict__ outi,
                     float* __restrict__ outl) {
  __shared__ __align__(16) unsigned char smem[49152];
  const int tid  = threadIdx.x;
  const int bm   = blockIdx.x;
  const int lane = tid & 63;
  const int wid  = tid >> 6;
  const int wr   = wid >> 1;
  const int wc   = wid & 1;
  const int l15  = lane & 15;
  const int lg   = lane >> 4;
  const int s_r  = tid >> 2;
  const int s_cb = (tid & 3) << 3;
  const float* aball = A + (size_t)(bm * 64 + s_r) * HD + s_cb;
  const float* bball = W + (size_t)s_r * HD + s_cb;
  const unsigned wswz  = ((unsigned)((s_r >> 1) & 3)) << 4;
  const unsigned wbyte = (unsigned)(s_r * 64) + (((unsigned)(s_cb * 2)) ^ wswz);
  f32x4 acc00 = {0.f,0.f,0.f,0.f}, acc01 = {0.f,0.f,0.f,0.f};
  f32x4 acc10 = {0.f,0.f,0.f,0.f}, acc11 = {0.f,0.f,0.f,0.f};
  float4 aE0, aE1, bE0, bE1, aO0, aO1, bO0, bO1;
#define LOADS(T, A0, A1, B0, B1) { \
    const float4* ap = (const float4*)(aball + (size_t)(T) * BKT); \
    A0 = ap[0]; A1 = ap[1]; \
    const float4* bp = (const float4*)(bball + (size_t)(T) * BKT); \
    B0 = bp[0]; B1 = bp[1]; }
#define CONVW2(BB, A0, A1, B0, B1) { \
    uint4 o0, o1, o2; \
    tsplit8(A0, A1, o0, o1, o2); \
    *(uint4*)(smem + (BB) +     0 + wbyte) = o0; \
    *(uint4*)(smem + (BB) +  4096 + wbyte) = o1; \
    *(uint4*)(smem + (BB) +  8192 + wbyte) = o2; \
    tsplit8(B0, B1, o0, o1, o2); \
    *(uint4*)(smem + (BB) + 12288 + wbyte) = o0; \
    *(uint4*)(smem + (BB) + 16384 + wbyte) = o1; \
    *(uint4*)(smem + (BB) + 20480 + wbyte) = o2; }
  auto compute = [&](int bb) {
    bf16x8 a0m0, a0m1, a1m0, a1m1, a2m0, a2m1;
    bf16x8 b0n0, b0n1, b1n0, b1n1, b2n0, b2n1;
    const unsigned kb = (unsigned)(lg * 16);
#define LDA(SI, MI, DST) { \
    int row = wr * 32 + (MI) * 16 + l15; \
    DST = *(const bf16x8*)(smem + bb + (SI) * 4096 + row * 64 + \
          (kb ^ ((((unsigned)row >> 1) & 3) << 4))); }
#define LDB(SI, NI, DST) { \
    int row = wc * 32 + (NI) * 16 + l15; \
    DST = *(const bf16x8*)(smem + bb + 12288 + (SI) * 4096 + row * 64 + \
          (kb ^ ((((unsigned)row >> 1) & 3) << 4))); }
    LDA(0, 0, a0m0) LDA(0, 1, a0m1)
    LDA(1, 0, a1m0) LDA(1, 1, a1m1)
    LDA(2, 0, a2m0) LDA(2, 1, a2m1)
    LDB(0, 0, b0n0) LDB(0, 1, b0n1)
    LDB(1, 0, b1n0) LDB(1, 1, b1n1)
    LDB(2, 0, b2n0) LDB(2, 1, b2n1)
#undef LDA
#undef LDB
    PROD1(a0m0, a0m1, b2n0, b2n1)
    PROD1(a1m0, a1m1, b1n0, b1n1)
    PROD1(a2m0, a2m1, b0n0, b0n1)
    PROD1(a0m0, a0m1, b1n0, b1n1)
    PROD1(a1m0, a1m1, b0n0, b0n1)
    PROD1(a0m0, a0m1, b0n0, b0n1)
  };
  LOADS(0, aE0, aE1, bE0, bE1)
  LOADS(1, aO0, aO1, bO0, bO1)
  CONVW2(0, aE0, aE1, bE0, bE1)
  __syncthreads();
#pragma unroll 1
  for (int kk = 0; kk < NKT; kk += 2) {
    if (kk + 2 < NKT) { LOADS(kk + 2, aE0, aE1, bE0, bE1) }
    __builtin_amdgcn_sched_barrier(0);
    compute(0);
    CONVW2(24576, aO0, aO1, bO0, bO1)
    __syncthreads();
    if (kk + 3 < NKT) { LOADS(kk + 3, aO0, aO1, bO0, bO1) }
    __builtin_amdgcn_sched_barrier(0);
    compute(24576);
    if (kk + 2 < NKT) { CONVW2(0, aE0, aE1, bE0, bE1) }
    __syncthreads();
  }
  const int t0 = bm * 64;
  float* lf2 = (float*)smem;
#define EPI(MI, NI, ACC) \
  { _Pragma("unroll") \
    for (int r = 0; r < 4; ++r) { \
      int tl = wr * 32 + (MI) * 16 + lg * 4 + r; \
      int e  = wc * 32 + (NI) * 16 + l15; \
      float v = ACC[r]; \
      outl[(size_t)(t0 + tl) * NE + e] = v; \
      lf2[tl * 65 + e] = v; \
    } }
  EPI(0, 0, acc00) EPI(0, 1, acc01) EPI(1, 0, acc10) EPI(1, 1, acc11)
#undef EPI
  __syncthreads();
  if (tid < 64) {
    const int t = tid;
    float m1 = -1e30f, m2 = -1e30f;
    int i1 = 0, i2 = 0;
#pragma unroll
    for (int e = 0; e < NE; ++e) {
      float v = lf2[t * 65 + e];
      if (v > m1)      { m2 = m1; i2 = i1; m1 = v; i1 = e; }
      else if (v > m2) { m2 = v; i2 = e; }
    }
    float e2  = expf(m2 - m1);
    float inv = 1.0f / (1.0f + e2);
    outw[(size_t)(t0 + t) * 2 + 0] = inv;
    outw[(size_t)(t0 + t) * 2 + 1] = e2 * inv;
    outi[(size_t)(t0 + t) * 2 + 0] = (float)i1;
    outi[(size_t)(t0 + t) * 2 + 1] = (float)i2;
  }
}

extern "C" void kernel_launch(void* const* d_in, const int* in_sizes, int n_in,
                              void* d_out, int out_size, void* d_ws, size_t ws_size,
                              hipStream_t stream) {
  (void)in_sizes; (void)n_in; (void)out_size;
  const float* A = (const float*)d_in[0];   // hidden_states [32768][4096] f32
  const float* W = (const float*)d_in[1];   // gate_w [64][4096] f32
  float* outw = (float*)d_out;              // [T][2] weights
  float* outi = (float*)d_out + 2 * TT;     // [T][2] indices AS FLOATS
  float* outl = (float*)d_out + 4 * TT;     // [T][64] logits

  const size_t need = (size_t)NKT * 3 * 4 * 1024;   // 1.5 MiB packed B
  if (ws_size >= need) {
    hipLaunchKernelGGL(prepack_w_kernel, dim3(128), dim3(256), 0, stream,
                       W, (uint4*)d_ws);
    hipLaunchKernelGGL(router_frag_kernel, dim3(TT / BROWS), dim3(NT), 0, stream,
                       A, (const uint4*)d_ws, outw, outi, outl);
  } else {
    hipLaunchKernelGGL(topk_router_lds, dim3(TT / 64), dim3(256), 0, stream,
                       A, W, outw, outi, outl);
  }
}

// Round 8
// 172.485 us; speedup vs baseline: 2.0249x; 1.1452x over previous
//
#include <hip/hip_runtime.h>

// TopKRouter: logits = hs[32768,4096] @ gate_w[64,4096]^T ; top-2 + softmax.
// f32 GEMM via 3-limb truncation split (6 MFMA products, si+sj<=2); limb
// values and per-accumulator product order identical to verified R3/R7.
//
// R8: DRAM-contiguity + zero-drain schedule.
//  - A staged RAW f32 via global_load_lds: each DMA instr = 1 KB contiguous
//    HBM burst; supertile = 3 K-steps (96 f32/row + 16B pad = 400 B rows),
//    buffer 25,600 B, double-buffered (51,200 B static LDS).
//  - A converted to bf16 limbs at fragment-read time (ds_read 32B -> tsplit).
//  - B from prepacked fragment-major limb table (R7-verified), 6 contiguous
//    1-KB L2 loads/wave/step, distance-1 register prefetch (named even/odd).
//  - One __syncthreads per supertile; every load crossing it has >=3 steps
//    (~4600 cyc) of lead -> the vmcnt(0) barrier drain is free.

#define NT    256
#define TT    32768
#define HD    4096
#define NE    64
#define BKT   32
#define NKT   128
#define BUFB  25600          // bytes per LDS A buffer (64 rows x 400 B)
#define ALIM  ((size_t)TT * HD * 4 - 16)

typedef __attribute__((ext_vector_type(8))) short bf16x8;
typedef __attribute__((ext_vector_type(4))) float f32x4;

#define MFMA __builtin_amdgcn_mfma_f32_16x16x32_bf16

__device__ __forceinline__ bf16x8 u2b(uint4 u) { return __builtin_bit_cast(bf16x8, u); }
__device__ __forceinline__ float4 b4f(uint4 u) { return __builtin_bit_cast(float4, u); }

__device__ __forceinline__ void gload_lds16(const void* g, void* l) {
  __builtin_amdgcn_global_load_lds(
      (const __attribute__((address_space(1))) void*)g,
      (__attribute__((address_space(3))) void*)l, 16, 0, 0);
}

// Exact 3-limb truncation split of 8 f32 -> 3 packed bf16x8 (as uint4).
__device__ __forceinline__ void tsplit8(float4 a, float4 b,
                                        uint4& o0, uint4& o1, uint4& o2) {
  float f[8] = {a.x, a.y, a.z, a.w, b.x, b.y, b.z, b.w};
  unsigned p0[4], p1[4], p2[4];
#pragma unroll
  for (int j = 0; j < 4; ++j) {
    float x0 = f[2 * j], x1 = f[2 * j + 1];
    unsigned u0 = __float_as_uint(x0) & 0xffff0000u;
    unsigned u1 = __float_as_uint(x1) & 0xffff0000u;
    float r0 = x0 - __uint_as_float(u0);
    float r1 = x1 - __uint_as_float(u1);
    unsigned v0 = __float_as_uint(r0) & 0xffff0000u;
    unsigned v1 = __float_as_uint(r1) & 0xffff0000u;
    float s0 = r0 - __uint_as_float(v0);
    float s1 = r1 - __uint_as_float(v1);
    p0[j] = (u0 >> 16) | u1;
    p1[j] = (v0 >> 16) | v1;
    p2[j] = (__float_as_uint(s0) >> 16) | (__float_as_uint(s1) & 0xffff0000u);
  }
  o0 = make_uint4(p0[0], p0[1], p0[2], p0[3]);
  o1 = make_uint4(p1[0], p1[1], p1[2], p1[3]);
  o2 = make_uint4(p2[0], p2[1], p2[2], p2[3]);
}

// ---- Pre-kernel: pack gate_w into fragment-major bf16 limb blocks ----
// uint4 index = ((t*3+s)*4+f)*64 + (lg*16 + (e&15)); verified in R7.
__global__ __launch_bounds__(256)
void prepack_w_kernel(const float* __restrict__ W, uint4* __restrict__ Bp) {
  const int t  = blockIdx.x * 256 + threadIdx.x;
  const int e  = t >> 9;
  const int k0 = (t & 511) * 8;
  const float4* wp = (const float4*)(W + (size_t)e * HD + k0);
  uint4 o0, o1, o2;
  tsplit8(wp[0], wp[1], o0, o1, o2);
  const int ts = k0 >> 5;
  const int lg = (k0 >> 3) & 3;
  const int f  = e >> 4;
  const int ln = lg * 16 + (e & 15);
  Bp[(((ts * 3 + 0) * 4 + f) << 6) + ln] = o0;
  Bp[(((ts * 3 + 1) * 4 + f) << 6) + ln] = o1;
  Bp[(((ts * 3 + 2) * 4 + f) << 6) + ln] = o2;
}

#define PROD1(AM0, AM1, BN0, BN1) \
    acc00 = MFMA(AM0, BN0, acc00, 0, 0, 0); \
    acc01 = MFMA(AM0, BN1, acc01, 0, 0, 0); \
    acc10 = MFMA(AM1, BN0, acc10, 0, 0, 0); \
    acc11 = MFMA(AM1, BN1, acc11, 0, 0, 0);

// ---- Main kernel ----
__global__ __launch_bounds__(NT, 2)
void router_dma_kernel(const float* __restrict__ A, const uint4* __restrict__ Bp,
                       float* __restrict__ outw, float* __restrict__ outi,
                       float* __restrict__ outl) {
  __shared__ __align__(16) unsigned char smem[2 * BUFB];   // 51,200 B

  const int tid  = threadIdx.x;
  const int bm   = blockIdx.x;
  const int lane = tid & 63;
  const int w    = tid >> 6;     // wave 0..3
  const int wr   = w >> 1;       // row half
  const int wc   = w & 1;        // expert half
  const int l15  = lane & 15;
  const int lg   = lane >> 4;    // 0..3

  const char* Abytes = (const char*)A;

  // DMA source offsets: slot j -> wave-instr i = j*4+w (valid i<25);
  // flat dest byte f = i*1024 + lane*16; row r = f/400, rb = f%400
  // (rb>=384 is pad: source row base, harmless re-read).
  size_t srcoff[7];
#pragma unroll
  for (int j = 0; j < 7; ++j) {
    int ii = j * 4 + w;
    int f  = ii * 1024 + lane * 16;
    int r  = f / 400, rb = f % 400;
    srcoff[j] = (size_t)(bm * 64 + r) * (HD * 4) + (size_t)(rb < 384 ? rb : 0);
  }

#define DMA_ISSUE(CT, BOFF) { \
    _Pragma("unroll") \
    for (int j = 0; j < 7; ++j) { \
      int ii = j * 4 + w; \
      if (ii < 25) { \
        size_t off = srcoff[j] + (size_t)(CT) * 384; \
        if (off > ALIM) off -= (size_t)(HD * 4); \
        gload_lds16(Abytes + off, smem + (BOFF) + ii * 1024); \
      } \
    } \
    __builtin_amdgcn_sched_barrier(0); }

  // Fragment-read bases: row = wr*32 + mi*16 + l15; byte = row*400 + s*128 + lg*32.
  const int row0b = (wr * 32 + l15) * 400;
  const int row1b = row0b + 16 * 400;
  const int lgb   = lg * 32;

  // B: fragment-major table; per step g, limb L, frag F in {0,1}:
  // uint4 idx = g*768 + L*256 + (wc*2+F)*64 + lane.
  const uint4* pbB = Bp + wc * 128 + lane;

  f32x4 acc00 = {0.f,0.f,0.f,0.f}, acc01 = {0.f,0.f,0.f,0.f};
  f32x4 acc10 = {0.f,0.f,0.f,0.f}, acc11 = {0.f,0.f,0.f,0.f};

  uint4 bA0f0, bA0f1, bA1f0, bA1f1, bA2f0, bA2f1;   // B limb regs, set A
  uint4 bB0f0, bB0f1, bB1f0, bB1f1, bB2f0, bB2f1;   // set B

#define LOADB(SET, G) { \
    const uint4* q_ = pbB + (size_t)(G) * 768; \
    SET##0f0 = q_[0];   SET##0f1 = q_[64]; \
    SET##1f0 = q_[256]; SET##1f1 = q_[320]; \
    SET##2f0 = q_[512]; SET##2f1 = q_[576]; }

  // One K-step: optional B prefetch (distance 1), 4x ds_read b128 raw A,
  // 2x tsplit8, 24 MFMA in R3's verified per-acc product order.
#define BSTEP(BOFF, S, BU, BL, GN, DOLOAD) { \
    if (DOLOAD) { LOADB(BL, GN) } \
    uint4 rA0lo = *(const uint4*)(smem + (BOFF) + row0b + (S) * 128 + lgb); \
    uint4 rA0hi = *(const uint4*)(smem + (BOFF) + row0b + (S) * 128 + lgb + 16); \
    uint4 rA1lo = *(const uint4*)(smem + (BOFF) + row1b + (S) * 128 + lgb); \
    uint4 rA1hi = *(const uint4*)(smem + (BOFF) + row1b + (S) * 128 + lgb + 16); \
    uint4 x0, x1, x2, y0, y1, y2; \
    tsplit8(b4f(rA0lo), b4f(rA0hi), x0, x1, x2); \
    tsplit8(b4f(rA1lo), b4f(rA1hi), y0, y1, y2); \
    const bf16x8 a0m0 = u2b(x0), a1m0 = u2b(x1), a2m0 = u2b(x2); \
    const bf16x8 a0m1 = u2b(y0), a1m1 = u2b(y1), a2m1 = u2b(y2); \
    PROD1(a0m0, a0m1, u2b(BU##2f0), u2b(BU##2f1)) \
    PROD1(a1m0, a1m1, u2b(BU##1f0), u2b(BU##1f1)) \
    PROD1(a2m0, a2m1, u2b(BU##0f0), u2b(BU##0f1)) \
    PROD1(a0m0, a0m1, u2b(BU##1f0), u2b(BU##1f1)) \
    PROD1(a1m0, a1m1, u2b(BU##0f0), u2b(BU##0f1)) \
    PROD1(a0m0, a0m1, u2b(BU##0f0), u2b(BU##0f1)) }

  // Prologue: DMA supertile 0 -> bufX(0); B(0) -> set A; barrier.
  DMA_ISSUE(0, 0)
  LOADB(bA, 0)
  __syncthreads();

  // Main: 21 outer iters x 2 supertiles (6 steps); steps 0..125.
#pragma unroll 1
  for (int ot = 0; ot < 21; ++ot) {
    const int g0 = ot * 6;
    DMA_ISSUE(2 * ot + 1, BUFB)            // supertile 2ot+1 -> bufY
    BSTEP(0, 0, bA, bB, g0 + 1, true)
    BSTEP(0, 1, bB, bA, g0 + 2, true)
    BSTEP(0, 2, bA, bB, g0 + 3, true)
    __syncthreads();                       // drains bufY DMA (3-step lead)
    DMA_ISSUE(2 * ot + 2, 0)               // supertile 2ot+2 -> bufX
    BSTEP(BUFB, 0, bB, bA, g0 + 4, true)
    BSTEP(BUFB, 1, bA, bB, g0 + 5, true)
    BSTEP(BUFB, 2, bB, bA, g0 + 6, true)
    __syncthreads();                       // drains bufX DMA (3-step lead)
  }

  // Tail: supertile 42 in bufX = steps 126,127.
  BSTEP(0, 0, bA, bB, 127, true)
  BSTEP(0, 1, bB, bA, 0, false)

  // ---- Epilogue: logits to global + LDS, then top-2 + softmax ----
  const int t0 = bm * 64;
  float* lf = (float*)smem;                // [64][65] f32 = 16.6 KB

  __syncthreads();                         // all ds_reads done before reuse

#define EPO(MI, NI, ACC) \
  { _Pragma("unroll") \
    for (int r = 0; r < 4; ++r) { \
      int tl = wr * 32 + (MI) * 16 + lg * 4 + r; \
      int e  = wc * 32 + (NI) * 16 + l15; \
      float v = ACC[r]; \
      outl[(size_t)(t0 + tl) * NE + e] = v; \
      lf[tl * 65 + e] = v; \
    } }
  EPO(0, 0, acc00) EPO(0, 1, acc01) EPO(1, 0, acc10) EPO(1, 1, acc11)
#undef EPO

  __syncthreads();

  if (tid < 64) {
    const int t = tid;
    float m1 = -1e30f, m2 = -1e30f;
    int i1 = 0, i2 = 0;
#pragma unroll
    for (int e = 0; e < NE; ++e) {
      float v = lf[t * 65 + e];
      if (v > m1)      { m2 = m1; i2 = i1; m1 = v; i1 = e; }
      else if (v > m2) { m2 = v; i2 = e; }
    }
    float e2  = expf(m2 - m1);
    float inv = 1.0f / (1.0f + e2);
    outw[(size_t)(t0 + t) * 2 + 0] = inv;
    outw[(size_t)(t0 + t) * 2 + 1] = e2 * inv;
    outi[(size_t)(t0 + t) * 2 + 0] = (float)i1;   // indices as floats
    outi[(size_t)(t0 + t) * 2 + 1] = (float)i2;
  }
}

// ---- Fallback (R3 LDS kernel, verified): used only if ws_size too small ----
__global__ __launch_bounds__(256, 2)
void topk_router_lds(const float* __restrict__ A, const float* __restrict__ W,
                     float* __restrict__ outw, float* __restrict__ outi,
                     float* __restrict__ outl) {
  __shared__ __align__(16) unsigned char smem[49152];
  const int tid  = threadIdx.x;
  const int bm   = blockIdx.x;
  const int lane = tid & 63;
  const int wid  = tid >> 6;
  const int wr   = wid >> 1;
  const int wc   = wid & 1;
  const int l15  = lane & 15;
  const int lg   = lane >> 4;
  const int s_r  = tid >> 2;
  const int s_cb = (tid & 3) << 3;
  const float* aball = A + (size_t)(bm * 64 + s_r) * HD + s_cb;
  const float* bball = W + (size_t)s_r * HD + s_cb;
  const unsigned wswz  = ((unsigned)((s_r >> 1) & 3)) << 4;
  const unsigned wbyte = (unsigned)(s_r * 64) + (((unsigned)(s_cb * 2)) ^ wswz);
  f32x4 acc00 = {0.f,0.f,0.f,0.f}, acc01 = {0.f,0.f,0.f,0.f};
  f32x4 acc10 = {0.f,0.f,0.f,0.f}, acc11 = {0.f,0.f,0.f,0.f};
  float4 aE0, aE1, bE0, bE1, aO0, aO1, bO0, bO1;
#define LOADS(T, A0, A1, B0, B1) { \
    const float4* ap = (const float4*)(aball + (size_t)(T) * BKT); \
    A0 = ap[0]; A1 = ap[1]; \
    const float4* bp = (const float4*)(bball + (size_t)(T) * BKT); \
    B0 = bp[0]; B1 = bp[1]; }
#define CONVW2(BB, A0, A1, B0, B1) { \
    uint4 o0, o1, o2; \
    tsplit8(A0, A1, o0, o1, o2); \
    *(uint4*)(smem + (BB) +     0 + wbyte) = o0; \
    *(uint4*)(smem + (BB) +  4096 + wbyte) = o1; \
    *(uint4*)(smem + (BB) +  8192 + wbyte) = o2; \
    tsplit8(B0, B1, o0, o1, o2); \
    *(uint4*)(smem + (BB) + 12288 + wbyte) = o0; \
    *(uint4*)(smem + (BB) + 16384 + wbyte) = o1; \
    *(uint4*)(smem + (BB) + 20480 + wbyte) = o2; }
  auto compute = [&](int bb) {
    bf16x8 a0m0, a0m1, a1m0, a1m1, a2m0, a2m1;
    bf16x8 b0n0, b0n1, b1n0, b1n1, b2n0, b2n1;
    const unsigned kb = (unsigned)(lg * 16);
#define LDA(SI, MI, DST) { \
    int row = wr * 32 + (MI) * 16 + l15; \
    DST = *(const bf16x8*)(smem + bb + (SI) * 4096 + row * 64 + \
          (kb ^ ((((unsigned)row >> 1) & 3) << 4))); }
#define LDB(SI, NI, DST) { \
    int row = wc * 32 + (NI) * 16 + l15; \
    DST = *(const bf16x8*)(smem + bb + 12288 + (SI) * 4096 + row * 64 + \
          (kb ^ ((((unsigned)row >> 1) & 3) << 4))); }
    LDA(0, 0, a0m0) LDA(0, 1, a0m1)
    LDA(1, 0, a1m0) LDA(1, 1, a1m1)
    LDA(2, 0, a2m0) LDA(2, 1, a2m1)
    LDB(0, 0, b0n0) LDB(0, 1, b0n1)
    LDB(1, 0, b1n0) LDB(1, 1, b1n1)
    LDB(2, 0, b2n0) LDB(2, 1, b2n1)
#undef LDA
#undef LDB
    PROD1(a0m0, a0m1, b2n0, b2n1)
    PROD1(a1m0, a1m1, b1n0, b1n1)
    PROD1(a2m0, a2m1, b0n0, b0n1)
    PROD1(a0m0, a0m1, b1n0, b1n1)
    PROD1(a1m0, a1m1, b0n0, b0n1)
    PROD1(a0m0, a0m1, b0n0, b0n1)
  };
  LOADS(0, aE0, aE1, bE0, bE1)
  LOADS(1, aO0, aO1, bO0, bO1)
  CONVW2(0, aE0, aE1, bE0, bE1)
  __syncthreads();
#pragma unroll 1
  for (int kk = 0; kk < NKT; kk += 2) {
    if (kk + 2 < NKT) { LOADS(kk + 2, aE0, aE1, bE0, bE1) }
    __builtin_amdgcn_sched_barrier(0);
    compute(0);
    CONVW2(24576, aO0, aO1, bO0, bO1)
    __syncthreads();
    if (kk + 3 < NKT) { LOADS(kk + 3, aO0, aO1, bO0, bO1) }
    __builtin_amdgcn_sched_barrier(0);
    compute(24576);
    if (kk + 2 < NKT) { CONVW2(0, aE0, aE1, bE0, bE1) }
    __syncthreads();
  }
  const int t0 = bm * 64;
  float* lf2 = (float*)smem;
#define EPI(MI, NI, ACC) \
  { _Pragma("unroll") \
    for (int r = 0; r < 4; ++r) { \
      int tl = wr * 32 + (MI) * 16 + lg * 4 + r; \
      int e  = wc * 32 + (NI) * 16 + l15; \
      float v = ACC[r]; \
      outl[(size_t)(t0 + tl) * NE + e] = v; \
      lf2[tl * 65 + e] = v; \
    } }
  EPI(0, 0, acc00) EPI(0, 1, acc01) EPI(1, 0, acc10) EPI(1, 1, acc11)
#undef EPI
  __syncthreads();
  if (tid < 64) {
    const int t = tid;
    float m1 = -1e30f, m2 = -1e30f;
    int i1 = 0, i2 = 0;
#pragma unroll
    for (int e = 0; e < NE; ++e) {
      float v = lf2[t * 65 + e];
      if (v > m1)      { m2 = m1; i2 = i1; m1 = v; i1 = e; }
      else if (v > m2) { m2 = v; i2 = e; }
    }
    float e2  = expf(m2 - m1);
    float inv = 1.0f / (1.0f + e2);
    outw[(size_t)(t0 + t) * 2 + 0] = inv;
    outw[(size_t)(t0 + t) * 2 + 1] = e2 * inv;
    outi[(size_t)(t0 + t) * 2 + 0] = (float)i1;
    outi[(size_t)(t0 + t) * 2 + 1] = (float)i2;
  }
}

extern "C" void kernel_launch(void* const* d_in, const int* in_sizes, int n_in,
                              void* d_out, int out_size, void* d_ws, size_t ws_size,
                              hipStream_t stream) {
  (void)in_sizes; (void)n_in; (void)out_size;
  const float* A = (const float*)d_in[0];   // hidden_states [32768][4096] f32
  const float* W = (const float*)d_in[1];   // gate_w [64][4096] f32
  float* outw = (float*)d_out;              // [T][2] weights
  float* outi = (float*)d_out + 2 * TT;     // [T][2] indices AS FLOATS
  float* outl = (float*)d_out + 4 * TT;     // [T][64] logits

  const size_t need = (size_t)NKT * 3 * 4 * 1024;   // 1.5 MiB packed B
  if (ws_size >= need) {
    hipLaunchKernelGGL(prepack_w_kernel, dim3(128), dim3(256), 0, stream,
                       W, (uint4*)d_ws);
    hipLaunchKernelGGL(router_dma_kernel, dim3(TT / 64), dim3(NT), 0, stream,
                       A, (const uint4*)d_ws, outw, outi, outl);
  } else {
    hipLaunchKernelGGL(topk_router_lds, dim3(TT / 64), dim3(256), 0, stream,
                       A, W, outw, outi, outl);
  }
}